// Round 5
// baseline (247.336 us; speedup 1.0000x reference)
//
#include <hip/hip_runtime.h>
#include <hip/hip_bf16.h>

constexpr int N_NODES = 20000;
constexpr int N_EDGES = 50000;
constexpr int IN_DIM  = 512;
constexpr int D       = 32;

typedef float vf4 __attribute__((ext_vector_type(4)));

// Workspace layout (4-byte units):
constexpr size_t OFF_DEG    = 0;         // int[20480]
constexpr size_t OFF_CURSOR = 20480;     // int[20480]
constexpr size_t OFF_START  = 40960;     // int[20480]
constexpr size_t OFF_SLOT   = 61440;     // int[100000]
constexpr size_t OFF_CVAL   = 161440;    // float[100000]
constexpr size_t OFF_MSG    = 262144;    // float[3200000]  (2E * 32)
constexpr size_t OFF_A      = 3462144;   // float[640000]
constexpr size_t OFF_B      = 4102144;   // float[640000]

__device__ __forceinline__ float dot4(vf4 a, vf4 b) {
    return fmaf(a.x, b.x, fmaf(a.y, b.y, fmaf(a.z, b.z, a.w * b.w)));
}

// ---------------------------------------------------------------------------
// h = relu(x @ W + b) -> A ; fused integer degree histogram (40 slots/block)
__global__ __launch_bounds__(256) void k_proj(const float* __restrict__ x,
                                              const float* __restrict__ W,
                                              const float* __restrict__ b,
                                              const int* __restrict__ ei,
                                              float* __restrict__ A,
                                              int* __restrict__ deg) {
    __shared__ float xs[8][IN_DIM];
    const int tid  = threadIdx.x;
    const int row0 = blockIdx.x * 8;

    if (tid < 40) atomicAdd(&deg[ei[blockIdx.x * 40 + tid]], 1);

    const vf4* xsrc = (const vf4*)(x + (size_t)row0 * IN_DIM);
    vf4* xdst = (vf4*)&xs[0][0];
    #pragma unroll
    for (int i = 0; i < 4; ++i)
        xdst[tid + 256 * i] = __builtin_nontemporal_load(&xsrc[tid + 256 * i]);
    __syncthreads();

    const int r = tid >> 5;
    const int c = tid & 31;
    const float* xr = xs[r];
    float acc = b[c];
    #pragma unroll 4
    for (int k = 0; k < IN_DIM; k += 4) {
        acc = fmaf(xr[k + 0], W[(k + 0) * D + c], acc);
        acc = fmaf(xr[k + 1], W[(k + 1) * D + c], acc);
        acc = fmaf(xr[k + 2], W[(k + 2) * D + c], acc);
        acc = fmaf(xr[k + 3], W[(k + 3) * D + c], acc);
    }
    A[(size_t)(row0 + r) * D + c] = fmaxf(acc, 0.0f);
}

// ---------------------------------------------------------------------------
// Exclusive prefix sum of deg[20000] -> start[20000]. One block, 1024 thr.
__global__ __launch_bounds__(1024) void k_scan(const int* __restrict__ deg,
                                               int* __restrict__ start) {
    __shared__ int sums[1024];
    const int tid  = threadIdx.x;
    const int base = tid * 20;
    int local[20];
    int s = 0;
    #pragma unroll
    for (int i = 0; i < 20; ++i) {
        const int idx = base + i;
        const int v = (idx < N_NODES) ? deg[idx] : 0;
        local[i] = v;
        s += v;
    }
    sums[tid] = s;
    __syncthreads();
    int acc = s;
    for (int off = 1; off < 1024; off <<= 1) {
        const int t = (tid >= off) ? sums[tid - off] : 0;
        __syncthreads();
        acc += t;
        sums[tid] = acc;
        __syncthreads();
    }
    int run = (tid > 0) ? sums[tid - 1] : 0;   // exclusive prefix
    #pragma unroll
    for (int i = 0; i < 20; ++i) {
        const int idx = base + i;
        if (idx < N_NODES) start[idx] = run;
        run += local[i];
    }
}

// ---------------------------------------------------------------------------
// slot_of[t] = start[out(t)] + next free position in out-node's list.
__global__ __launch_bounds__(256) void k_place(const int* __restrict__ ei,
                                               const int* __restrict__ start,
                                               int* __restrict__ cursor,
                                               int* __restrict__ slot_of) {
    const int t = blockIdx.x * 256 + threadIdx.x;
    if (t >= 2 * N_EDGES) return;
    const int* src = ei;
    const int* dst = ei + N_EDGES;
    const int e = (t < N_EDGES) ? t : t - N_EDGES;
    const int out = (t < N_EDGES) ? dst[e] : src[e];
    const int slot = atomicAdd(&cursor[out], 1);
    slot_of[t] = start[out] + slot;
}

// ---------------------------------------------------------------------------
// One wave per TWO transports. msg[slot] = c * (T[t] @ h[in]) (128 B store),
// cval[slot] = c. No atomics.
// T load: instr j, lane l -> contiguous elem j*256+l*4; row j*8+(l>>3), chunk l&7.
__global__ __launch_bounds__(256) void k_edge(const float* __restrict__ T,
                                              const float* __restrict__ rw,
                                              const float* __restrict__ alpha_p,
                                              const int* __restrict__ src,
                                              const int* __restrict__ dst,
                                              const int* __restrict__ deg,
                                              const int* __restrict__ slot_of,
                                              const float* __restrict__ hA,
                                              float* __restrict__ msg,
                                              float* __restrict__ cval) {
    const int wave = (blockIdx.x * 256 + threadIdx.x) >> 6;
    const int lane = threadIdx.x & 63;
    const int t0 = wave * 2;
    const int t1 = t0 + 1;

    int in0, out0, in1, out1;
    {
        int e0 = (t0 < N_EDGES) ? t0 : t0 - N_EDGES;
        if (t0 < N_EDGES) { in0 = src[e0]; out0 = dst[e0]; }
        else              { in0 = dst[e0]; out0 = src[e0]; }
        int e1 = (t1 < N_EDGES) ? t1 : t1 - N_EDGES;
        if (t1 < N_EDGES) { in1 = src[e1]; out1 = dst[e1]; }
        else              { in1 = dst[e1]; out1 = src[e1]; }
    }
    const int slot0 = slot_of[t0];
    const int slot1 = slot_of[t1];

    const int m = lane & 7;

    const vf4* T0p = (const vf4*)(T + (size_t)t0 * (D * D));
    const vf4* T1p = (const vf4*)(T + (size_t)t1 * (D * D));
    vf4 a00 = __builtin_nontemporal_load(&T0p[lane]);
    vf4 a01 = __builtin_nontemporal_load(&T0p[64 + lane]);
    vf4 a02 = __builtin_nontemporal_load(&T0p[128 + lane]);
    vf4 a03 = __builtin_nontemporal_load(&T0p[192 + lane]);
    vf4 a10 = __builtin_nontemporal_load(&T1p[lane]);
    vf4 a11 = __builtin_nontemporal_load(&T1p[64 + lane]);
    vf4 a12 = __builtin_nontemporal_load(&T1p[128 + lane]);
    vf4 a13 = __builtin_nontemporal_load(&T1p[192 + lane]);
    vf4 h0 = ((const vf4*)(hA + (size_t)in0 * D))[m];
    vf4 h1 = ((const vf4*)(hA + (size_t)in1 * D))[m];

    const float alpha = alpha_p[0];
    const float c0 = alpha * log1pf(expf(rw[t0])) / fmaxf((float)deg[out0], 1.0f);
    const float c1 = alpha * log1pf(expf(rw[t1])) / fmaxf((float)deg[out1], 1.0f);

    float p00 = dot4(a00, h0), p01 = dot4(a01, h0), p02 = dot4(a02, h0), p03 = dot4(a03, h0);
    float p10 = dot4(a10, h1), p11 = dot4(a11, h1), p12 = dot4(a12, h1), p13 = dot4(a13, h1);

    #define RED8(p) { p += __shfl_xor(p, 1); p += __shfl_xor(p, 2); p += __shfl_xor(p, 4); }
    RED8(p00) RED8(p01) RED8(p02) RED8(p03)
    RED8(p10) RED8(p11) RED8(p12) RED8(p13)
    #undef RED8

    // redistribute so lane r (mod 32) holds row r; row = j*8+g, source lane (r&7)*8
    const int srcl = (lane & 7) * 8;
    const float v00 = __shfl(p00, srcl), v01 = __shfl(p01, srcl),
                v02 = __shfl(p02, srcl), v03 = __shfl(p03, srcl);
    const float v10 = __shfl(p10, srcl), v11 = __shfl(p11, srcl),
                v12 = __shfl(p12, srcl), v13 = __shfl(p13, srcl);

    if (lane < 32) {
        const float y = (lane < 8) ? v00 : (lane < 16) ? v01 : (lane < 24) ? v02 : v03;
        msg[(size_t)slot0 * D + lane] = c0 * y;
        if (lane == 0) cval[slot0] = c0;
    } else {
        const int r = lane - 32;
        const float y = (r < 8) ? v10 : (r < 16) ? v11 : (r < 24) ? v12 : v13;
        msg[(size_t)slot1 * D + r] = c1 * y;
        if (r == 0) cval[slot1] = c1;
    }
}

// ---------------------------------------------------------------------------
// One wave per node: sum the node's contiguous message slab + cval,
// h' = h*(1-csum)+acc, LayerNorm, ReLU -> dest.
__global__ __launch_bounds__(256) void k_comb(const int* __restrict__ deg,
                                              const int* __restrict__ start,
                                              const float* __restrict__ msg,
                                              const float* __restrict__ cval,
                                              const float* __restrict__ hA,
                                              const float* __restrict__ gam,
                                              const float* __restrict__ bet,
                                              float* __restrict__ dest) {
    const int lane = threadIdx.x & 63;
    const int node = blockIdx.x * 4 + (threadIdx.x >> 6);
    const int d    = deg[node];
    const int st   = start[node];

    const int sl  = lane >> 5;   // 0/1: which of two slots this half handles
    const int col = lane & 31;

    float acc = 0.0f, csum = 0.0f;
    for (int k = 0; k < d; k += 2) {
        const int s = k + sl;
        if (s < d) {
            acc += msg[(size_t)(st + s) * D + col];
            if (col == 0) csum += cval[st + s];
        }
    }
    // combine the two halves
    acc  += __shfl_xor(acc, 32);
    csum += __shfl_xor(csum, 32);
    csum  = __shfl(csum, sl * 32);          // broadcast from col==0 of own half
    csum += __shfl_xor(csum, 32);           // ensure both halves identical
    csum *= 0.5f;                           // counted twice by the two adds

    if (lane < 32) {
        const float hv = hA[(size_t)node * D + lane];
        const float v  = hv * (1.0f - csum) + acc;

        float s = v;
        #pragma unroll
        for (int msk = 16; msk >= 1; msk >>= 1) s += __shfl_xor(s, msk);
        const float mu = s * (1.0f / 32.0f);
        const float dv = v - mu;
        float q = dv * dv;
        #pragma unroll
        for (int msk = 16; msk >= 1; msk >>= 1) q += __shfl_xor(q, msk);
        const float var = q * (1.0f / 32.0f);

        float y = dv * rsqrtf(var + 1e-5f) * gam[lane] + bet[lane];
        dest[(size_t)node * D + lane] = fmaxf(y, 0.0f);
    }
}

// ---------------------------------------------------------------------------
extern "C" void kernel_launch(void* const* d_in, const int* in_sizes, int n_in,
                              void* d_out, int out_size, void* d_ws, size_t ws_size,
                              hipStream_t stream) {
    const float* x      = (const float*)d_in[0];
    const int*   ei     = (const int*)  d_in[1];   // [2, E]: src row | dst row
    const float* W      = (const float*)d_in[2];
    const float* b      = (const float*)d_in[3];
    const float* alpha0 = (const float*)d_in[4];
    const float* T0     = (const float*)d_in[5];
    const float* rw0    = (const float*)d_in[6];
    const float* g0     = (const float*)d_in[7];
    const float* be0    = (const float*)d_in[8];
    const float* alpha1 = (const float*)d_in[9];
    const float* T1     = (const float*)d_in[10];
    const float* rw1    = (const float*)d_in[11];
    const float* g1     = (const float*)d_in[12];
    const float* be1    = (const float*)d_in[13];

    float* out = (float*)d_out;
    int*   wsi = (int*)d_ws;
    float* wsf = (float*)d_ws;

    int*   deg    = wsi + OFF_DEG;
    int*   cursor = wsi + OFF_CURSOR;
    int*   start  = wsi + OFF_START;
    int*   slotof = wsi + OFF_SLOT;
    float* cval   = wsf + OFF_CVAL;
    float* msg    = wsf + OFF_MSG;
    float* A      = wsf + OFF_A;
    float* B      = wsf + OFF_B;

    const int* src = ei;
    const int* dst = ei + N_EDGES;

    // zero deg + cursor in one memset
    (void)hipMemsetAsync(wsi, 0, 2 * 20480 * sizeof(int), stream);

    k_proj <<<N_NODES / 8, 256, 0, stream>>>(x, W, b, ei, A, deg);
    k_scan <<<1, 1024, 0, stream>>>(deg, start);
    k_place<<<(2 * N_EDGES + 255) / 256, 256, 0, stream>>>(ei, start, cursor, slotof);

    const int edge_blocks = (2 * N_EDGES) / 8;   // 2 transports/wave, 4 waves/block
    k_edge<<<edge_blocks, 256, 0, stream>>>(T0, rw0, alpha0, src, dst, deg, slotof, A, msg, cval);
    k_comb<<<N_NODES / 4, 256, 0, stream>>>(deg, start, msg, cval, A, g0, be0, B);

    k_edge<<<edge_blocks, 256, 0, stream>>>(T1, rw1, alpha1, src, dst, deg, slotof, B, msg, cval);
    k_comb<<<N_NODES / 4, 256, 0, stream>>>(deg, start, msg, cval, B, g1, be1, out);
}